// Round 10
// baseline (278.048 us; speedup 1.0000x reference)
//
#include <hip/hip_runtime.h>
#include <hip/hip_fp16.h>

typedef _Float16 half8 __attribute__((ext_vector_type(8)));
typedef _Float16 half4 __attribute__((ext_vector_type(4)));
typedef __fp16  fp16x2 __attribute__((ext_vector_type(2)));
typedef float f32x4 __attribute__((ext_vector_type(4)));

#define BB 4
#define NB 8
#define LL 512
#define SS 512
#define HH 8
#define EE 64
#define ROWSTRIDE (HH * EE)   // 512 floats between consecutive l (or s) rows

__device__ __forceinline__ unsigned pkh(float a, float b) {
    union { fp16x2 h; unsigned u; } c;
    c.h = __builtin_amdgcn_cvt_pkrtz(a, b);
    return c.u;
}

// R4 base (82 us) + T15 two-tile pipeline done via MACROS (R7 lesson: lambda
// array-ref params break SROA -> scratch spill; textual phases keep pA/pB in
// named function-scope arrays with static indices).
// Schedule per tile t: stage_load(t+1); QK(t) [MFMA] overlapped with
// softmax-finish+PV(t-1) [trans/VALU + MFMA on other buffer]; barrier;
// stage_write(t+1); barrier.  2 blocks/CU, S-tile 64 (L2 sweet spot, R5).

#define QK_PHASE(KRB, KIB, PP, MX) do {                                        \
    float tmax_ = 0.f;                                                         \
    const char* KR_ = (const char*)(KRB);                                      \
    const char* KI_ = (const char*)(KIB);                                      \
    _Pragma("unroll")                                                          \
    for (int n = 0; n < 4; ++n) {                                              \
        int srow = n * 16 + l16;                                               \
        int rb   = srow * 128;                                                 \
        int swz  = (srow & 7) << 4;                                            \
        half8 kr0 = *(const half8*)(KR_ + rb + ((lgrp * 16)      ^ swz));      \
        half8 kr1 = *(const half8*)(KR_ + rb + ((64 + lgrp * 16) ^ swz));      \
        half8 ki0 = *(const half8*)(KI_ + rb + ((lgrp * 16)      ^ swz));      \
        half8 ki1 = *(const half8*)(KI_ + rb + ((64 + lgrp * 16) ^ swz));      \
        f32x4 z = (f32x4){0.f,0.f,0.f,0.f};                                    \
        z = __builtin_amdgcn_mfma_f32_16x16x32_f16(kr0, qr[0],  z, 0, 0, 0);   \
        z = __builtin_amdgcn_mfma_f32_16x16x32_f16(kr1, qr[1],  z, 0, 0, 0);   \
        z = __builtin_amdgcn_mfma_f32_16x16x32_f16(ki0, qin[0], z, 0, 0, 0);   \
        z = __builtin_amdgcn_mfma_f32_16x16x32_f16(ki1, qin[1], z, 0, 0, 0);   \
        f32x4 w = (f32x4){0.f,0.f,0.f,0.f};                                    \
        w = __builtin_amdgcn_mfma_f32_16x16x32_f16(ki0, qr[0],  w, 0, 0, 0);   \
        w = __builtin_amdgcn_mfma_f32_16x16x32_f16(ki1, qr[1],  w, 0, 0, 0);   \
        w = __builtin_amdgcn_mfma_f32_16x16x32_f16(kr0, qin[0], w, 0, 0, 0);   \
        w = __builtin_amdgcn_mfma_f32_16x16x32_f16(kr1, qin[1], w, 0, 0, 0);   \
        _Pragma("unroll")                                                      \
        for (int r = 0; r < 4; ++r) {                                          \
            float mg = __builtin_amdgcn_sqrtf(z[r] * z[r] + w[r] * w[r]);      \
            PP[n][r] = mg;                                                     \
            tmax_ = fmaxf(tmax_, mg);                                          \
        }                                                                      \
    }                                                                          \
    MX = tmax_;                                                                \
} while (0)

#define FINISH_PHASE(VRB, VIB, PP, MX) do {                                    \
    float tmax_ = fmaxf(MX, __shfl_xor(MX, 16));                               \
    tmax_ = fmaxf(tmax_, __shfl_xor(tmax_, 32));                               \
    float mn_ = fmaxf(m, tmax_);                                               \
    if (__any(tmax_ > m)) {                                                    \
        float sc_ = __expf(m - mn_);                                           \
        lsum *= sc_;                                                           \
        float scr_[4];                                                         \
        _Pragma("unroll")                                                      \
        for (int r = 0; r < 4; ++r) scr_[r] = __shfl(sc_, lgrp * 4 + r);       \
        _Pragma("unroll")                                                      \
        for (int n = 0; n < 4; ++n) {                                          \
            _Pragma("unroll")                                                  \
            for (int r = 0; r < 4; ++r) {                                      \
                ore[n][r] *= scr_[r];                                          \
                oim[n][r] *= scr_[r];                                          \
            }                                                                  \
        }                                                                      \
    }                                                                          \
    m = mn_;                                                                   \
    float ps_ = 0.f;                                                           \
    _Pragma("unroll")                                                          \
    for (int n = 0; n < 4; ++n) {                                              \
        _Pragma("unroll")                                                      \
        for (int r = 0; r < 4; ++r) {                                          \
            float pe_ = __expf(PP[n][r] - mn_);                                \
            PP[n][r] = pe_;                                                    \
            ps_ += pe_;                                                        \
        }                                                                      \
        uint2 val_;                                                            \
        val_.x = pkh(PP[n][0], PP[n][1]);                                      \
        val_.y = pkh(PP[n][2], PP[n][3]);                                      \
        *reinterpret_cast<uint2*>(Pw + prow + ((n * 32 + lgrp * 8) ^ pswz)) = val_; \
    }                                                                          \
    ps_ += __shfl_xor(ps_, 16);                                                \
    ps_ += __shfl_xor(ps_, 32);                                                \
    lsum += ps_;                                                               \
    const char* VR_ = (const char*)(VRB);                                      \
    const char* VI_ = (const char*)(VIB);                                      \
    _Pragma("unroll")                                                          \
    for (int kc = 0; kc < 2; ++kc) {                                           \
        half8 pa_ = *reinterpret_cast<const half8*>(Pw + prow + ((kc * 64 + lgrp * 16) ^ pswz)); \
        int sb2_ = (kc * 32 + lgrp * 8) * 2;                                   \
        _Pragma("unroll")                                                      \
        for (int nd = 0; nd < 4; ++nd) {                                       \
            int d_  = nd * 16 + l16;                                           \
            int vo_ = d_ * 128 + (sb2_ ^ ((d_ & 7) << 4));                     \
            half8 vr_ = *(const half8*)(VR_ + vo_);                            \
            half8 vi_ = *(const half8*)(VI_ + vo_);                            \
            ore[nd] = __builtin_amdgcn_mfma_f32_16x16x32_f16(pa_, vr_, ore[nd], 0, 0, 0); \
            oim[nd] = __builtin_amdgcn_mfma_f32_16x16x32_f16(pa_, vi_, oim[nd], 0, 0, 0); \
        }                                                                      \
    }                                                                          \
} while (0)

__global__ __launch_bounds__(512, 4) void cattn_kernel(
    const float* __restrict__ qre, const float* __restrict__ qim,
    const float* __restrict__ kre, const float* __restrict__ kim,
    const float* __restrict__ vre, const float* __restrict__ vim,
    float* __restrict__ out)
{
    // 80 KiB total LDS -> 2 blocks/CU
    __shared__ __align__(16) _Float16 KtRe[2][64 * 64];  // [buf][s][e] swizzled
    __shared__ __align__(16) _Float16 KtIm[2][64 * 64];
    __shared__ __align__(16) _Float16 VtRe[2][64 * 64];  // [buf][d][s] swizzled
    __shared__ __align__(16) _Float16 VtIm[2][64 * 64];
    __shared__ __align__(16) _Float16 Pbuf[8][16 * 64];  // per-wave P[l][s] swizzled

    const int tid  = threadIdx.x;
    const int wave = tid >> 6;
    const int lane = tid & 63;
    const int lgrp = lane >> 4;   // 0..3
    const int l16  = lane & 15;   // 0..15

    // bijective XCD swizzle: nwg=1024, 8 XCDs, 128 blocks per XCD chunk
    const int bid  = blockIdx.x;
    const int nid  = (bid & 7) * 128 + (bid >> 3);
    const int lt   = nid & 3;     // L-tile (128 rows)
    const int head = nid >> 2;    // 0..255
    const int h    = head & 7;
    const int bn   = head >> 3;

    const size_t headQ = (size_t)bn * LL * ROWSTRIDE + (size_t)h * EE;
    const size_t headK = (size_t)bn * SS * ROWSTRIDE + (size_t)h * EE;

    // staging registers (T14: load-early / write-late)
    float4 ka[2], kb[2];   // K: 2 items x 8 f32
    float4 vv[4];          // V: 4 s-rows x 4 d-cols

    const int kEc0  = tid & 7;               // e-chunk
    const int kS0   = (tid >> 3) & 63;       // s-row
    const int vArr  = tid >> 8;
    const int vD0   = (tid & 15) * 4;
    const int vS0   = ((tid >> 4) & 15) * 4;

    auto stage_load = [&](int st) {
        const int tb = st * 64;
        {
            const float* p = kre + headK + (size_t)(tb + kS0) * ROWSTRIDE + kEc0 * 8;
            ka[0] = *(const float4*)p;
            kb[0] = *(const float4*)(p + 4);
        }
        {
            const float* p = kim + headK + (size_t)(tb + kS0) * ROWSTRIDE + kEc0 * 8;
            ka[1] = *(const float4*)p;
            kb[1] = *(const float4*)(p + 4);
        }
        {
            const float* src = vArr ? vim : vre;
            #pragma unroll
            for (int i = 0; i < 4; ++i)
                vv[i] = *(const float4*)(src + headK + (size_t)(tb + vS0 + i) * ROWSTRIDE + vD0);
        }
    };

    auto stage_write = [&](int buf) {
        #pragma unroll
        for (int it = 0; it < 2; ++it) {
            union { half8 h; unsigned u[4]; } kv;
            kv.u[0] = pkh(ka[it].x, ka[it].y);
            kv.u[1] = pkh(ka[it].z, ka[it].w);
            kv.u[2] = pkh(kb[it].x, kb[it].y);
            kv.u[3] = pkh(kb[it].z, kb[it].w);
            _Float16* base = it ? KtIm[buf] : KtRe[buf];
            *reinterpret_cast<half8*>(reinterpret_cast<char*>(base) +
                kS0 * 128 + ((kEc0 * 16) ^ ((kS0 & 7) << 4))) = kv.h;
        }
        {
            _Float16* base = vArr ? VtIm[buf] : VtRe[buf];
            #pragma unroll
            for (int dd = 0; dd < 4; ++dd) {
                int d = vD0 + dd;
                union { half4 h; unsigned u[2]; } hv;
                hv.u[0] = pkh((&vv[0].x)[dd], (&vv[1].x)[dd]);
                hv.u[1] = pkh((&vv[2].x)[dd], (&vv[3].x)[dd]);
                *reinterpret_cast<half4*>(reinterpret_cast<char*>(base) +
                    d * 128 + ((vS0 * 2) ^ ((d & 7) << 4))) = hv.h;
            }
        }
    };

    // ---------------- Q fragments (B-operand: lane holds Q[l=l16][e=lgrp*8+j]) --
    const int l0 = lt * 128 + wave * 16;
    half8 qr[2], qin[2];   // qr and -qi
    {
        size_t base = headQ + (size_t)(l0 + l16) * ROWSTRIDE + lgrp * 8;
        #pragma unroll
        for (int ec = 0; ec < 2; ++ec) {
            float4 a0 = *(const float4*)(qre + base + ec * 32);
            float4 a1 = *(const float4*)(qre + base + ec * 32 + 4);
            float4 b0 = *(const float4*)(qim + base + ec * 32);
            float4 b1 = *(const float4*)(qim + base + ec * 32 + 4);
            #pragma unroll
            for (int j = 0; j < 4; ++j) {
                qr[ec][j]      = (_Float16)((&a0.x)[j]);
                qr[ec][4 + j]  = (_Float16)((&a1.x)[j]);
                qin[ec][j]     = (_Float16)(-(&b0.x)[j]);
                qin[ec][4 + j] = (_Float16)(-(&b1.x)[j]);
            }
        }
    }

    f32x4 ore[4], oim[4];
    #pragma unroll
    for (int n = 0; n < 4; ++n) { ore[n] = (f32x4){0.f,0.f,0.f,0.f}; oim[n] = (f32x4){0.f,0.f,0.f,0.f}; }
    float m = -1e30f, lsum = 0.f;

    char* Pw = reinterpret_cast<char*>(&Pbuf[wave][0]);
    const int prow = l16 * 128;
    const int pswz = (l16 & 7) << 4;

    float pA[4][4], pB[4][4];
    float mxA, mxB;

    // ---------------- prologue: tile 0 ----------------
    stage_load(0);
    stage_write(0);
    __syncthreads();

    stage_load(1);
    QK_PHASE(KtRe[0], KtIm[0], pA, mxA);
    stage_write(1);                 // buf1 unread so far: no barrier needed before
    __syncthreads();                // buf1 ready

    // ---------------- pipelined pairs: tiles (1,2), (3,4), (5,6) ----------------
    for (int tp = 0; tp < 3; ++tp) {
        // odd tile 2tp+1 (buf1); finish tile 2tp (buf0)
        stage_load(2 * tp + 2);
        QK_PHASE(KtRe[1], KtIm[1], pB, mxB);
        FINISH_PHASE(VtRe[0], VtIm[0], pA, mxA);
        __syncthreads();            // V0 reads done -> buf0 reusable
        stage_write(0);             // tile 2tp+2 -> buf0
        __syncthreads();            // buf0 ready
        // even tile 2tp+2 (buf0); finish tile 2tp+1 (buf1)
        stage_load(2 * tp + 3);
        QK_PHASE(KtRe[0], KtIm[0], pA, mxA);
        FINISH_PHASE(VtRe[1], VtIm[1], pB, mxB);
        __syncthreads();            // V1 reads done -> buf1 reusable
        stage_write(1);             // tile 2tp+3 -> buf1
        __syncthreads();            // buf1 ready
    }

    // ---------------- tail: tile 7 (buf1); finish 6 then 7 ----------------
    QK_PHASE(KtRe[1], KtIm[1], pB, mxB);
    FINISH_PHASE(VtRe[0], VtIm[0], pA, mxA);   // tile 6
    FINISH_PHASE(VtRe[1], VtIm[1], pB, mxB);   // tile 7

    // ---------------- epilogue: O[l = lgrp*4+r][d = nd*16+l16] ----------------
    const size_t outImOff = (size_t)BB * NB * LL * HH * EE;
    #pragma unroll
    for (int r = 0; r < 4; ++r) {
        int lrow = l0 + lgrp * 4 + r;
        float ls  = __shfl(lsum, lgrp * 4 + r);
        float inv = 1.f / ls;
        size_t obase = ((size_t)bn * LL + lrow) * ROWSTRIDE + (size_t)h * EE;
        #pragma unroll
        for (int nd = 0; nd < 4; ++nd) {
            int d = nd * 16 + l16;
            out[obase + d]            = ore[nd][r] * inv;
            out[outImOff + obase + d] = oim[nd][r] * inv;
        }
    }
}

extern "C" void kernel_launch(void* const* d_in, const int* in_sizes, int n_in,
                              void* d_out, int out_size, void* d_ws, size_t ws_size,
                              hipStream_t stream) {
    const float* qre = (const float*)d_in[0];
    const float* qim = (const float*)d_in[1];
    const float* kre = (const float*)d_in[2];
    const float* kim = (const float*)d_in[3];
    const float* vre = (const float*)d_in[4];
    const float* vim = (const float*)d_in[5];
    float* out = (float*)d_out;
    dim3 grid(1024), block(512);
    hipLaunchKernelGGL(cattn_kernel, grid, block, 0, stream,
                       qre, qim, kre, kim, vre, vim, out);
}

// Round 11
// 84.563 us; speedup vs baseline: 3.2880x; 3.2880x over previous
//
#include <hip/hip_runtime.h>
#include <hip/hip_fp16.h>

typedef _Float16 half8 __attribute__((ext_vector_type(8)));
typedef _Float16 half4 __attribute__((ext_vector_type(4)));
typedef __fp16  fp16x2 __attribute__((ext_vector_type(2)));
typedef float f32x4 __attribute__((ext_vector_type(4)));

#define BB 4
#define NB 8
#define LL 512
#define SS 512
#define HH 8
#define EE 64
#define ROWSTRIDE (HH * EE)   // 512 floats between consecutive l (or s) rows

__device__ __forceinline__ unsigned pkh(float a, float b) {
    union { fp16x2 h; unsigned u; } c;
    c.h = __builtin_amdgcn_cvt_pkrtz(a, b);
    return c.u;
}

// R4 base (82 us) with merged re/im 256B LDS rows + 4-bit XOR swizzle.
// Why: 128B rows = one bank period -> rows alias banks; (row&7)<<4 gives only
// 8 slots -> 8 lanes/slot from 8 rows = 8-way conflict on every K/V b128 read
// (the constant 8.4M SQ_LDS_BANK_CONFLICT). 256B rows + (row&15)<<4 -> 16
// slots, 4 lanes/slot = 4-way. Same LDS footprint (80 KiB, 2 blocks/CU).
// R5 lesson: 2 blocks/CU + S-tile 64 is the L2-locality sweet spot.
// R7/R9 lesson: two-tile pipeline exceeds the 128-VGPR budget -> spills; dead.

__global__ __launch_bounds__(512, 4) void cattn_kernel(
    const float* __restrict__ qre, const float* __restrict__ qim,
    const float* __restrict__ kre, const float* __restrict__ kim,
    const float* __restrict__ vre, const float* __restrict__ vim,
    float* __restrict__ out)
{
    // 80 KiB total LDS -> 2 blocks/CU
    __shared__ __align__(16) _Float16 Kt[2][64 * 128];  // [buf] row s: [re e0..63 | im e0..63], swizzled
    __shared__ __align__(16) _Float16 Vt[2][64 * 128];  // [buf] row d: [re s0..63 | im s0..63], swizzled
    __shared__ __align__(16) _Float16 Pbuf[8][16 * 64]; // per-wave P[l][s] swizzled

    const int tid  = threadIdx.x;
    const int wave = tid >> 6;
    const int lane = tid & 63;
    const int lgrp = lane >> 4;   // 0..3
    const int l16  = lane & 15;   // 0..15

    // bijective XCD swizzle: nwg=1024, 8 XCDs, 128 blocks per XCD chunk
    const int bid  = blockIdx.x;
    const int nid  = (bid & 7) * 128 + (bid >> 3);
    const int lt   = nid & 3;     // L-tile (128 rows)
    const int head = nid >> 2;    // 0..255
    const int h    = head & 7;
    const int bn   = head >> 3;

    const size_t headQ = (size_t)bn * LL * ROWSTRIDE + (size_t)h * EE;
    const size_t headK = (size_t)bn * SS * ROWSTRIDE + (size_t)h * EE;

    // staging registers (T14: load-early / write-late)
    float4 ka[2], kb[2];   // K: re/im x 8 f32
    float4 vv[4];          // V: 4 s-rows x 4 d-cols

    const int kEc0  = tid & 7;               // e-chunk
    const int kS0   = (tid >> 3) & 63;       // s-row
    const int vArr  = tid >> 8;              // 0 = re half, 1 = im half
    const int vD0   = (tid & 15) * 4;
    const int vS0   = ((tid >> 4) & 15) * 4;

    auto stage_load = [&](int st) {
        const int tb = st * 64;
        {
            const float* p = kre + headK + (size_t)(tb + kS0) * ROWSTRIDE + kEc0 * 8;
            ka[0] = *(const float4*)p;
            kb[0] = *(const float4*)(p + 4);
        }
        {
            const float* p = kim + headK + (size_t)(tb + kS0) * ROWSTRIDE + kEc0 * 8;
            ka[1] = *(const float4*)p;
            kb[1] = *(const float4*)(p + 4);
        }
        {
            const float* src = vArr ? vim : vre;
            #pragma unroll
            for (int i = 0; i < 4; ++i)
                vv[i] = *(const float4*)(src + headK + (size_t)(tb + vS0 + i) * ROWSTRIDE + vD0);
        }
    };

    auto stage_write = [&](int buf) {
        {
            char* kdst = reinterpret_cast<char*>(Kt[buf]) + kS0 * 256;
            const int kswz = (kS0 & 15) << 4;
            #pragma unroll
            for (int it = 0; it < 2; ++it) {   // it=0 re (col 0..127), it=1 im (col 128..255)
                union { half8 h; unsigned u[4]; } kv;
                kv.u[0] = pkh(ka[it].x, ka[it].y);
                kv.u[1] = pkh(ka[it].z, ka[it].w);
                kv.u[2] = pkh(kb[it].x, kb[it].y);
                kv.u[3] = pkh(kb[it].z, kb[it].w);
                *reinterpret_cast<half8*>(kdst + ((it * 128 + kEc0 * 16) ^ kswz)) = kv.h;
            }
        }
        {
            char* vbase = reinterpret_cast<char*>(Vt[buf]);
            #pragma unroll
            for (int dd = 0; dd < 4; ++dd) {
                int d = vD0 + dd;
                union { half4 h; unsigned u[2]; } hv;
                hv.u[0] = pkh((&vv[0].x)[dd], (&vv[1].x)[dd]);
                hv.u[1] = pkh((&vv[2].x)[dd], (&vv[3].x)[dd]);
                *reinterpret_cast<half4*>(vbase + d * 256 +
                    ((vArr * 128 + vS0 * 2) ^ ((d & 15) << 4))) = hv.h;
            }
        }
    };

    // ---------------- Q fragments (B-operand: lane holds Q[l=l16][e=lgrp*8+j]) --
    const int l0 = lt * 128 + wave * 16;
    half8 qr[2], qin[2];   // qr and -qi
    {
        size_t base = headQ + (size_t)(l0 + l16) * ROWSTRIDE + lgrp * 8;
        #pragma unroll
        for (int ec = 0; ec < 2; ++ec) {
            float4 a0 = *(const float4*)(qre + base + ec * 32);
            float4 a1 = *(const float4*)(qre + base + ec * 32 + 4);
            float4 b0 = *(const float4*)(qim + base + ec * 32);
            float4 b1 = *(const float4*)(qim + base + ec * 32 + 4);
            #pragma unroll
            for (int j = 0; j < 4; ++j) {
                qr[ec][j]      = (_Float16)((&a0.x)[j]);
                qr[ec][4 + j]  = (_Float16)((&a1.x)[j]);
                qin[ec][j]     = (_Float16)(-(&b0.x)[j]);
                qin[ec][4 + j] = (_Float16)(-(&b1.x)[j]);
            }
        }
    }

    f32x4 ore[4], oim[4];
    #pragma unroll
    for (int n = 0; n < 4; ++n) { ore[n] = (f32x4){0.f,0.f,0.f,0.f}; oim[n] = (f32x4){0.f,0.f,0.f,0.f}; }
    float m = -1e30f, lsum = 0.f;

    stage_load(0);
    stage_write(0);
    __syncthreads();

    char* Pw = reinterpret_cast<char*>(&Pbuf[wave][0]);
    const int prow = l16 * 128;
    const int pswz = (l16 & 7) << 4;

    // ---------------- main loop over 8 S-tiles ----------------
    for (int st = 0; st < 8; ++st) {
        const int cur = st & 1;
        if (st < 7) stage_load(st + 1);   // loads in flight during compute

        const char* Kb = (const char*)Kt[cur];
        const char* Vb = (const char*)Vt[cur];

        // scores^T: lane holds mag[s = n*16 + lgrp*4 + r][l = l16]
        float p_[4][4];
        float tmax = 0.f;
        #pragma unroll
        for (int n = 0; n < 4; ++n) {
            int srow = n * 16 + l16;
            int rb   = srow * 256;
            int swz  = (srow & 15) << 4;
            half8 kr0 = *(const half8*)(Kb + rb + ((lgrp * 16)       ^ swz));
            half8 kr1 = *(const half8*)(Kb + rb + ((64  + lgrp * 16) ^ swz));
            half8 ki0 = *(const half8*)(Kb + rb + ((128 + lgrp * 16) ^ swz));
            half8 ki1 = *(const half8*)(Kb + rb + ((192 + lgrp * 16) ^ swz));
            f32x4 z = (f32x4){0.f,0.f,0.f,0.f};
            z = __builtin_amdgcn_mfma_f32_16x16x32_f16(kr0, qr[0],  z, 0, 0, 0);
            z = __builtin_amdgcn_mfma_f32_16x16x32_f16(kr1, qr[1],  z, 0, 0, 0);
            z = __builtin_amdgcn_mfma_f32_16x16x32_f16(ki0, qin[0], z, 0, 0, 0);
            z = __builtin_amdgcn_mfma_f32_16x16x32_f16(ki1, qin[1], z, 0, 0, 0);
            f32x4 w = (f32x4){0.f,0.f,0.f,0.f};
            w = __builtin_amdgcn_mfma_f32_16x16x32_f16(ki0, qr[0],  w, 0, 0, 0);
            w = __builtin_amdgcn_mfma_f32_16x16x32_f16(ki1, qr[1],  w, 0, 0, 0);
            w = __builtin_amdgcn_mfma_f32_16x16x32_f16(kr0, qin[0], w, 0, 0, 0);
            w = __builtin_amdgcn_mfma_f32_16x16x32_f16(kr1, qin[1], w, 0, 0, 0);
            #pragma unroll
            for (int r = 0; r < 4; ++r) {
                float mg = __builtin_amdgcn_sqrtf(z[r] * z[r] + w[r] * w[r]);
                p_[n][r] = mg;
                tmax = fmaxf(tmax, mg);
            }
        }

        // online softmax, one row per lane (4-way replicated across lgrps)
        tmax = fmaxf(tmax, __shfl_xor(tmax, 16));
        tmax = fmaxf(tmax, __shfl_xor(tmax, 32));
        float mn = fmaxf(m, tmax);
        // exact defer: if no row's max grew, sc == exp(0) == 1 -> skip rescale
        if (__any(tmax > m)) {
            float sc = __expf(m - mn);
            lsum *= sc;
            float scr[4];
            #pragma unroll
            for (int r = 0; r < 4; ++r) scr[r] = __shfl(sc, lgrp * 4 + r);
            #pragma unroll
            for (int n = 0; n < 4; ++n)
                #pragma unroll
                for (int r = 0; r < 4; ++r) { ore[n][r] *= scr[r]; oim[n][r] *= scr[r]; }
        }
        m = mn;
        float ps = 0.f;
        #pragma unroll
        for (int n = 0; n < 4; ++n)
            #pragma unroll
            for (int r = 0; r < 4; ++r) {
                float pe = __expf(p_[n][r] - mn);
                p_[n][r] = pe;
                ps += pe;
            }
        ps += __shfl_xor(ps, 16);
        ps += __shfl_xor(ps, 32);
        lsum += ps;

        // write P rows to per-wave LDS: row l16, s-run n*16+lgrp*4..+3 (8B each)
        #pragma unroll
        for (int n = 0; n < 4; ++n) {
            uint2 val;
            val.x = pkh(p_[n][0], p_[n][1]);
            val.y = pkh(p_[n][2], p_[n][3]);
            *reinterpret_cast<uint2*>(Pw + prow + ((n * 32 + lgrp * 8) ^ pswz)) = val;
        }

        // PV: read A-frag P[l16][kc*32+lgrp*8 ..+7] from LDS, mfma against V^T
        #pragma unroll
        for (int kc = 0; kc < 2; ++kc) {
            half8 pa = *reinterpret_cast<const half8*>(Pw + prow + ((kc * 64 + lgrp * 16) ^ pswz));
            int sb2 = kc * 64 + lgrp * 16;   // byte col within the re half
            #pragma unroll
            for (int nd = 0; nd < 4; ++nd) {
                int d    = nd * 16 + l16;
                int rbv  = d * 256;
                int vswz = (d & 15) << 4;
                half8 vr = *(const half8*)(Vb + rbv + (sb2 ^ vswz));
                half8 vi = *(const half8*)(Vb + rbv + ((128 + sb2) ^ vswz));
                ore[nd] = __builtin_amdgcn_mfma_f32_16x16x32_f16(pa, vr, ore[nd], 0, 0, 0);
                oim[nd] = __builtin_amdgcn_mfma_f32_16x16x32_f16(pa, vi, oim[nd], 0, 0, 0);
            }
        }

        if (st < 7) stage_write(cur ^ 1);  // convert + LDS write AFTER compute
        __syncthreads();
    }

    // ---------------- epilogue: O[l = lgrp*4+r][d = nd*16+l16] ----------------
    const size_t outImOff = (size_t)BB * NB * LL * HH * EE;
    #pragma unroll
    for (int r = 0; r < 4; ++r) {
        int lrow = l0 + lgrp * 4 + r;
        float ls  = __shfl(lsum, lgrp * 4 + r);
        float inv = 1.f / ls;
        size_t obase = ((size_t)bn * LL + lrow) * ROWSTRIDE + (size_t)h * EE;
        #pragma unroll
        for (int nd = 0; nd < 4; ++nd) {
            int d = nd * 16 + l16;
            out[obase + d]            = ore[nd][r] * inv;
            out[outImOff + obase + d] = oim[nd][r] * inv;
        }
    }
}

extern "C" void kernel_launch(void* const* d_in, const int* in_sizes, int n_in,
                              void* d_out, int out_size, void* d_ws, size_t ws_size,
                              hipStream_t stream) {
    const float* qre = (const float*)d_in[0];
    const float* qim = (const float*)d_in[1];
    const float* kre = (const float*)d_in[2];
    const float* kim = (const float*)d_in[3];
    const float* vre = (const float*)d_in[4];
    const float* vim = (const float*)d_in[5];
    float* out = (float*)d_out;
    dim3 grid(1024), block(512);
    hipLaunchKernelGGL(cattn_kernel, grid, block, 0, stream,
                       qre, qim, kre, kim, vre, vim, out);
}